// Round 2
// baseline (134.737 us; speedup 1.0000x reference)
//
#include <hip/hip_runtime.h>
#include <cstdint>
#include <cstddef>

#define BATCH 8
#define SEQ 1024
#define DIM 768
#define EPS_K 1e-7f

typedef __bf16 bf16x8 __attribute__((ext_vector_type(8)));
typedef float f32x4 __attribute__((ext_vector_type(4)));
typedef uint16_t u16x4 __attribute__((ext_vector_type(4)));

__device__ __forceinline__ uint16_t f2bf(float f) {
  union { float f; uint32_t u; } v; v.f = f;
  uint32_t u = v.u;
  u += 0x7FFFu + ((u >> 16) & 1u);   // RNE to bf16
  return (uint16_t)(u >> 16);
}

__device__ __forceinline__ void gload16(const void* g, void* l) {
  __builtin_amdgcn_global_load_lds(
      (const __attribute__((address_space(1))) uint32_t*)g,
      (__attribute__((address_space(3))) uint32_t*)l, 16, 0, 0);
}

// ---------------------------------------------------------------------------
// Kernel 1: fp32 -> bf16 convert, producing row-major ab[b][s][d] and
// transposed at[b][d][s]; blocks with x==0 also zero their den slice.
// ---------------------------------------------------------------------------
__global__ __launch_bounds__(256) void convert_kernel(const float* __restrict__ A,
                                                      uint16_t* __restrict__ ab,
                                                      uint16_t* __restrict__ at,
                                                      float* __restrict__ den) {
  const int b  = blockIdx.z;
  const int s0 = blockIdx.y * 64;
  const int d0 = blockIdx.x * 64;
  __shared__ uint16_t tl[64][66];          // 66 stride: column reads 2-way (free)
  const int c  = threadIdx.x & 63;
  const int r0 = threadIdx.x >> 6;         // 0..3
  if (blockIdx.x == 0 && threadIdx.x < 64) den[b * SEQ + s0 + threadIdx.x] = 0.f;
  const float* Ab = A + (size_t)b * SEQ * DIM;
  uint16_t* abb = ab + (size_t)b * SEQ * DIM;
#pragma unroll
  for (int i = 0; i < 16; ++i) {
    int r = r0 + i * 4;
    uint16_t h = f2bf(Ab[(size_t)(s0 + r) * DIM + d0 + c]);
    abb[(size_t)(s0 + r) * DIM + d0 + c] = h;
    tl[r][c] = h;
  }
  __syncthreads();
  uint16_t* atb = at + (size_t)b * DIM * SEQ;
#pragma unroll
  for (int i = 0; i < 16; ++i) {
    int r = r0 + i * 4;                    // local d index
    atb[(size_t)(d0 + r) * SEQ + s0 + c] = tl[c][r];
  }
}

// ---------------------------------------------------------------------------
// Kernel 2 (symmetric): for tile pair (i<=j) compute
//   E = exp(Q_i·Q_j^T) * m_i * m_j   (128x128)
// write P[i-tile][j-tile]; if i!=j also write the mirrored tile P[j][i]
// (bit-identical by symmetry). Accumulate den row-sums (i rows) and, for
// off-diagonal blocks, col-sums (= row-sums of the mirrored j rows).
// ---------------------------------------------------------------------------
__global__ __launch_bounds__(256) void scores_kernel(const uint16_t* __restrict__ ab,
                                                     const int* __restrict__ mask,
                                                     uint16_t* __restrict__ P,
                                                     float* __restrict__ den) {
  const int b = blockIdx.z;
  // decode upper-triangular tile pair: idx in [0,36) -> (i,j), i<=j, 8x8 tiles
  int rem = blockIdx.x, ti = 0;
#pragma unroll
  for (int it = 0; it < 8; ++it) { if (rem >= 8 - ti) { rem -= 8 - ti; ++ti; } }
  const int tj   = ti + rem;
  const int s0   = ti * 128;
  const int t0   = tj * 128;
  const bool diag = (ti == tj);

  const int tid  = threadIdx.x;
  const int lane = tid & 63;
  const int wid  = tid >> 6;
  const int wr   = wid >> 1;   // wave row (queries)
  const int wc   = wid & 1;    // wave col (keys)

  __shared__ uint16_t ldsQ[128 * 32];
  __shared__ uint16_t ldsK[128 * 32];
  __shared__ float mrow[128];
  __shared__ float mcol[128];

  if (tid < 128)        mrow[tid]       = (float)mask[b * SEQ + s0 + tid];
  else                  mcol[tid - 128] = (float)mask[b * SEQ + t0 + (tid - 128)];

  const uint16_t* aQ = ab + (size_t)b * SEQ * DIM + (size_t)s0 * DIM;
  const uint16_t* aK = ab + (size_t)b * SEQ * DIM + (size_t)t0 * DIM;

  f32x4 acc[4][4];
#pragma unroll
  for (int m = 0; m < 4; ++m)
#pragma unroll
    for (int n = 0; n < 4; ++n) acc[m][n] = f32x4{0.f, 0.f, 0.f, 0.f};

  for (int k0 = 0; k0 < DIM; k0 += 32) {
    __syncthreads();                       // previous tile consumed
#pragma unroll
    for (int i = 0; i < 2; ++i) {
      int idx = (i * 256 + tid) * 8;       // linear elem idx in [128][32] tile
      int r = idx >> 5, c = idx & 31;
      gload16(aQ + (size_t)r * DIM + k0 + c, &ldsQ[idx]);
      gload16(aK + (size_t)r * DIM + k0 + c, &ldsK[idx]);
    }
    __syncthreads();                       // loads landed

    bf16x8 qf[4], kf[4];
    const int rowQ = wr * 64 + (lane & 15);
    const int rowK = wc * 64 + (lane & 15);
    const int kch  = (lane >> 4) * 8;
#pragma unroll
    for (int m = 0; m < 4; ++m) qf[m] = *(const bf16x8*)&ldsQ[(rowQ + m * 16) * 32 + kch];
#pragma unroll
    for (int n = 0; n < 4; ++n) kf[n] = *(const bf16x8*)&ldsK[(rowK + n * 16) * 32 + kch];
#pragma unroll
    for (int m = 0; m < 4; ++m)
#pragma unroll
      for (int n = 0; n < 4; ++n)
        acc[m][n] = __builtin_amdgcn_mfma_f32_16x16x32_bf16(qf[m], kf[n], acc[m][n], 0, 0, 0);
  }

  // Epilogue: e = exp(S)*m_q*m_t; write P tile (and mirror if off-diag);
  // accumulate row sums (q-rows) and col sums (t-rows, off-diag only).
  uint16_t* Pb = P + (size_t)b * SEQ * SEQ;
  float colAcc[4] = {0.f, 0.f, 0.f, 0.f};
#pragma unroll
  for (int m = 0; m < 4; ++m) {
    float rsj[4] = {0.f, 0.f, 0.f, 0.f};
    const int qb = wr * 64 + m * 16 + (lane >> 4) * 4;   // local q base (j adds 0..3)
#pragma unroll
    for (int n = 0; n < 4; ++n) {
      const int tloc = wc * 64 + n * 16 + (lane & 15);   // local t
      const float mc = mcol[tloc];
      u16x4 tr;
#pragma unroll
      for (int j = 0; j < 4; ++j) {
        float e = __expf(acc[m][n][j]) * mrow[qb + j] * mc;
        rsj[j]    += e;
        colAcc[n] += e;
        uint16_t h = f2bf(e);
        tr[j] = h;
        Pb[(size_t)(s0 + qb + j) * SEQ + t0 + tloc] = h;  // row-major write
      }
      if (!diag) {                                        // mirrored tile, 8B store
        *(u16x4*)&Pb[(size_t)(t0 + tloc) * SEQ + s0 + qb] = tr;
      }
    }
#pragma unroll
    for (int j = 0; j < 4; ++j) {
      float rs = rsj[j];
      rs += __shfl_xor(rs, 1);
      rs += __shfl_xor(rs, 2);
      rs += __shfl_xor(rs, 4);
      rs += __shfl_xor(rs, 8);
      if ((lane & 15) == 0) atomicAdd(&den[b * SEQ + s0 + qb + j], rs);
    }
  }
  if (!diag) {
#pragma unroll
    for (int n = 0; n < 4; ++n) {
      float cs = colAcc[n];
      cs += __shfl_xor(cs, 16);
      cs += __shfl_xor(cs, 32);
      if (lane < 16) atomicAdd(&den[b * SEQ + t0 + wc * 64 + n * 16 + lane], cs);
    }
  }
}

// ---------------------------------------------------------------------------
// Kernel 3: out[b][q][d] = (1/(den[q]+eps)) * sum_t P[q][t] * at[d][t]
// ---------------------------------------------------------------------------
__global__ __launch_bounds__(256) void out_kernel(const uint16_t* __restrict__ P,
                                                  const uint16_t* __restrict__ at,
                                                  const float* __restrict__ den,
                                                  float* __restrict__ out) {
  const int b   = blockIdx.z;
  const int q0  = blockIdx.y * 128;
  const int d0  = blockIdx.x * 128;
  const int tid = threadIdx.x;
  const int lane = tid & 63;
  const int wid  = tid >> 6;
  const int wr   = wid >> 1;
  const int wc   = wid & 1;

  __shared__ uint16_t ldsP[128 * 32];
  __shared__ uint16_t ldsA[128 * 32];
  __shared__ float rden[128];

  if (tid < 128) rden[tid] = 1.0f / (den[b * SEQ + q0 + tid] + EPS_K);

  const uint16_t* Pb = P  + (size_t)b * SEQ * SEQ + (size_t)q0 * SEQ;
  const uint16_t* Ab = at + (size_t)b * DIM * SEQ + (size_t)d0 * SEQ;

  f32x4 acc[4][4];
#pragma unroll
  for (int m = 0; m < 4; ++m)
#pragma unroll
    for (int n = 0; n < 4; ++n) acc[m][n] = f32x4{0.f, 0.f, 0.f, 0.f};

  for (int k0 = 0; k0 < SEQ; k0 += 32) {
    __syncthreads();
#pragma unroll
    for (int i = 0; i < 2; ++i) {
      int idx = (i * 256 + tid) * 8;
      int r = idx >> 5, c = idx & 31;
      gload16(Pb + (size_t)r * SEQ + k0 + c, &ldsP[idx]);
      gload16(Ab + (size_t)r * SEQ + k0 + c, &ldsA[idx]);
    }
    __syncthreads();

    bf16x8 pf[4], af[4];
    const int rowP = wr * 64 + (lane & 15);
    const int rowA = wc * 64 + (lane & 15);
    const int kch  = (lane >> 4) * 8;
#pragma unroll
    for (int m = 0; m < 4; ++m) pf[m] = *(const bf16x8*)&ldsP[(rowP + m * 16) * 32 + kch];
#pragma unroll
    for (int n = 0; n < 4; ++n) af[n] = *(const bf16x8*)&ldsA[(rowA + n * 16) * 32 + kch];
#pragma unroll
    for (int m = 0; m < 4; ++m)
#pragma unroll
      for (int n = 0; n < 4; ++n)
        acc[m][n] = __builtin_amdgcn_mfma_f32_16x16x32_bf16(pf[m], af[n], acc[m][n], 0, 0, 0);
  }

  float* ob = out + (size_t)b * SEQ * DIM;
#pragma unroll
  for (int m = 0; m < 4; ++m) {
#pragma unroll
    for (int j = 0; j < 4; ++j) {
      const int ql = wr * 64 + m * 16 + (lane >> 4) * 4 + j;
      const float sc = rden[ql];
#pragma unroll
      for (int n = 0; n < 4; ++n) {
        const int dl = d0 + wc * 64 + n * 16 + (lane & 15);
        ob[(size_t)(q0 + ql) * DIM + dl] = acc[m][n][j] * sc;
      }
    }
  }
}

// ---------------------------------------------------------------------------
extern "C" void kernel_launch(void* const* d_in, const int* in_sizes, int n_in,
                              void* d_out, int out_size, void* d_ws, size_t ws_size,
                              hipStream_t stream) {
  (void)in_sizes; (void)n_in; (void)out_size; (void)ws_size;
  const float* A    = (const float*)d_in[0];
  const int*   mask = (const int*)d_in[1];
  float*       out  = (float*)d_out;

  char* ws = (char*)d_ws;
  const size_t NB_AB = (size_t)BATCH * SEQ * DIM * 2;   // 12,582,912
  const size_t NB_AT = NB_AB;                            // 12,582,912
  const size_t NB_P  = (size_t)BATCH * SEQ * SEQ * 2;   // 16,777,216
  uint16_t* ab  = (uint16_t*)(ws);
  uint16_t* at  = (uint16_t*)(ws + NB_AB);
  uint16_t* P   = (uint16_t*)(ws + NB_AB + NB_AT);
  float*    den = (float*)   (ws + NB_AB + NB_AT + NB_P);

  dim3 blk(256);
  convert_kernel<<<dim3(DIM / 64, SEQ / 64, BATCH), blk, 0, stream>>>(A, ab, at, den);
  scores_kernel<<<dim3(36, 1, BATCH), blk, 0, stream>>>(ab, mask, P, den);
  out_kernel<<<dim3(DIM / 128, SEQ / 128, BATCH), blk, 0, stream>>>(P, at, den, out);
}

// Round 3
// 118.633 us; speedup vs baseline: 1.1357x; 1.1357x over previous
//
#include <hip/hip_runtime.h>
#include <cstdint>
#include <cstddef>

#define BATCH 8
#define SEQ 1024
#define DIM 768
#define EPS_K 1e-7f

typedef __bf16 bf16x8 __attribute__((ext_vector_type(8)));
typedef float f32x4 __attribute__((ext_vector_type(4)));

__device__ __forceinline__ uint16_t f2bf(float f) {
  union { float f; uint32_t u; } v; v.f = f;
  uint32_t u = v.u;
  u += 0x7FFFu + ((u >> 16) & 1u);   // RNE to bf16
  return (uint16_t)(u >> 16);
}

__device__ __forceinline__ void gload16(const void* g, void* l) {
  __builtin_amdgcn_global_load_lds(
      (const __attribute__((address_space(1))) uint32_t*)g,
      (__attribute__((address_space(3))) uint32_t*)l, 16, 0, 0);
}

// ---------------------------------------------------------------------------
// Kernel 1: fp32 -> bf16 convert, producing row-major ab[b][s][d] and
// transposed at[b][d][s] (so both GEMMs read operands as [row][8 contig k]).
// ---------------------------------------------------------------------------
__global__ __launch_bounds__(256) void convert_kernel(const float* __restrict__ A,
                                                      uint16_t* __restrict__ ab,
                                                      uint16_t* __restrict__ at) {
  const int b  = blockIdx.z;
  const int s0 = blockIdx.y * 64;
  const int d0 = blockIdx.x * 64;
  __shared__ uint16_t tl[64][66];          // 66 stride: column reads 2-way (free)
  const int c  = threadIdx.x & 63;
  const int r0 = threadIdx.x >> 6;         // 0..3
  const float* Ab = A + (size_t)b * SEQ * DIM;
  uint16_t* abb = ab + (size_t)b * SEQ * DIM;
#pragma unroll
  for (int i = 0; i < 16; ++i) {
    int r = r0 + i * 4;
    uint16_t h = f2bf(Ab[(size_t)(s0 + r) * DIM + d0 + c]);
    abb[(size_t)(s0 + r) * DIM + d0 + c] = h;
    tl[r][c] = h;
  }
  __syncthreads();
  uint16_t* atb = at + (size_t)b * DIM * SEQ;
#pragma unroll
  for (int i = 0; i < 16; ++i) {
    int r = r0 + i * 4;                    // local d index
    atb[(size_t)(d0 + r) * SEQ + s0 + c] = tl[c][r];
  }
}

// ---------------------------------------------------------------------------
// Kernel 2: P[b][q][t] = m_q * m_t * exp( ab[q]·ab[t] )   (bf16)
// 128x128 tile, 4 waves (2x2), 16x16x32 bf16 MFMA.
// 2-phase loop: prefetch next K-tile before compute, ONE barrier per K-step.
// 1D grid, batch = bid&7 so each batch pins to one XCD (L2 holds its panel).
// ---------------------------------------------------------------------------
__global__ __launch_bounds__(256) void scores_kernel(const uint16_t* __restrict__ ab,
                                                     const int* __restrict__ mask,
                                                     uint16_t* __restrict__ P) {
  const int b    = blockIdx.x & 7;
  const int tile = blockIdx.x >> 3;        // 0..63
  const int s0   = (tile >> 3) * 128;
  const int t0   = (tile & 7) * 128;

  const int tid  = threadIdx.x;
  const int lane = tid & 63;
  const int wid  = tid >> 6;
  const int wr   = wid >> 1;   // wave row (queries)
  const int wc   = wid & 1;    // wave col (keys)

  __shared__ uint16_t ldsQ[2][128 * 32];
  __shared__ uint16_t ldsK[2][128 * 32];
  __shared__ float mrow[128];
  __shared__ float mcol[128];

  if (tid < 128)        mrow[tid]       = (float)mask[b * SEQ + s0 + tid];
  else                  mcol[tid - 128] = (float)mask[b * SEQ + t0 + (tid - 128)];

  const uint16_t* aQ = ab + (size_t)b * SEQ * DIM + (size_t)s0 * DIM;
  const uint16_t* aK = ab + (size_t)b * SEQ * DIM + (size_t)t0 * DIM;

  // stage K-tile k0 into buffer buf (per-thread: two 16B chunks per operand)
  const int sr = (tid * 8) >> 5;           // row 0..63  (first half)
  const int sc = (tid * 8) & 31;           // col within 32
#define STAGE(buf, k0)                                                         \
  do {                                                                         \
    int _i0 = tid * 8, _i1 = (256 + tid) * 8;                                  \
    gload16(aQ + (size_t)sr * DIM + (k0) + sc,        &ldsQ[buf][_i0]);        \
    gload16(aQ + (size_t)(sr + 64) * DIM + (k0) + sc, &ldsQ[buf][_i1]);        \
    gload16(aK + (size_t)sr * DIM + (k0) + sc,        &ldsK[buf][_i0]);        \
    gload16(aK + (size_t)(sr + 64) * DIM + (k0) + sc, &ldsK[buf][_i1]);        \
  } while (0)

  f32x4 acc[4][4];
#pragma unroll
  for (int m = 0; m < 4; ++m)
#pragma unroll
    for (int n = 0; n < 4; ++n) acc[m][n] = f32x4{0.f, 0.f, 0.f, 0.f};

  STAGE(0, 0);
  __syncthreads();                          // prologue drain (vmcnt0 + barrier)

  const int rowQ = wr * 64 + (lane & 15);
  const int rowK = wc * 64 + (lane & 15);
  const int kch  = (lane >> 4) * 8;

  int cur = 0;
  for (int k0 = 0; k0 < DIM; k0 += 32) {
    if (k0 + 32 < DIM) STAGE(cur ^ 1, k0 + 32);   // issue next-tile loads first

    bf16x8 qf[4], kf[4];
#pragma unroll
    for (int m = 0; m < 4; ++m) qf[m] = *(const bf16x8*)&ldsQ[cur][(rowQ + m * 16) * 32 + kch];
#pragma unroll
    for (int n = 0; n < 4; ++n) kf[n] = *(const bf16x8*)&ldsK[cur][(rowK + n * 16) * 32 + kch];
#pragma unroll
    for (int m = 0; m < 4; ++m)
#pragma unroll
      for (int n = 0; n < 4; ++n)
        acc[m][n] = __builtin_amdgcn_mfma_f32_16x16x32_bf16(qf[m], kf[n], acc[m][n], 0, 0, 0);

    __syncthreads();                        // drains prefetch vmcnt + barrier
    cur ^= 1;
  }
#undef STAGE

  // Epilogue: e = exp(S)*m_q*m_t, write bf16 P.
  uint16_t* Pb = P + (size_t)b * SEQ * SEQ;
#pragma unroll
  for (int m = 0; m < 4; ++m) {
    const int qb = wr * 64 + m * 16 + (lane >> 4) * 4;   // local q base (+j)
#pragma unroll
    for (int n = 0; n < 4; ++n) {
      const int tloc = wc * 64 + n * 16 + (lane & 15);
      const float mc = mcol[tloc];
#pragma unroll
      for (int j = 0; j < 4; ++j) {
        float e = __expf(acc[m][n][j]) * mrow[qb + j] * mc;
        Pb[(size_t)(s0 + qb + j) * SEQ + t0 + tloc] = f2bf(e);
      }
    }
  }
}

// ---------------------------------------------------------------------------
// Kernel 3: out[b][q][d] = (1/(den_q+eps)) * sum_t P[q][t] * at[d][t]
// den computed IN-KERNEL via ones-B MFMA: accd[m] = sum_k pf[m][k] — its C/D
// row (m*16+(lane>>4)*4+j) matches exactly the rows this lane writes.
// ---------------------------------------------------------------------------
__global__ __launch_bounds__(256) void out_kernel(const uint16_t* __restrict__ P,
                                                  const uint16_t* __restrict__ at,
                                                  float* __restrict__ out) {
  const int b    = blockIdx.x & 7;
  const int tile = blockIdx.x >> 3;        // 0..47
  const int q0   = (tile / 6) * 128;
  const int d0   = (tile % 6) * 128;

  const int tid  = threadIdx.x;
  const int lane = tid & 63;
  const int wid  = tid >> 6;
  const int wr   = wid >> 1;
  const int wc   = wid & 1;

  __shared__ uint16_t ldsP[2][128 * 32];
  __shared__ uint16_t ldsA[2][128 * 32];

  const uint16_t* Pb = P  + (size_t)b * SEQ * SEQ + (size_t)q0 * SEQ;
  const uint16_t* Ab = at + (size_t)b * DIM * SEQ + (size_t)d0 * SEQ;

  const int sr = (tid * 8) >> 5;
  const int sc = (tid * 8) & 31;
#define STAGE(buf, k0)                                                         \
  do {                                                                         \
    int _i0 = tid * 8, _i1 = (256 + tid) * 8;                                  \
    gload16(Pb + (size_t)sr * SEQ + (k0) + sc,        &ldsP[buf][_i0]);        \
    gload16(Pb + (size_t)(sr + 64) * SEQ + (k0) + sc, &ldsP[buf][_i1]);        \
    gload16(Ab + (size_t)sr * SEQ + (k0) + sc,        &ldsA[buf][_i0]);        \
    gload16(Ab + (size_t)(sr + 64) * SEQ + (k0) + sc, &ldsA[buf][_i1]);        \
  } while (0)

  f32x4 acc[4][4];
  f32x4 accd[4];
#pragma unroll
  for (int m = 0; m < 4; ++m) {
    accd[m] = f32x4{0.f, 0.f, 0.f, 0.f};
#pragma unroll
    for (int n = 0; n < 4; ++n) acc[m][n] = f32x4{0.f, 0.f, 0.f, 0.f};
  }

  bf16x8 onesf;
#pragma unroll
  for (int i = 0; i < 8; ++i) onesf[i] = (__bf16)1.0f;

  STAGE(0, 0);
  __syncthreads();

  const int rowP = wr * 64 + (lane & 15);
  const int rowA = wc * 64 + (lane & 15);
  const int kch  = (lane >> 4) * 8;

  int cur = 0;
  for (int k0 = 0; k0 < SEQ; k0 += 32) {
    if (k0 + 32 < SEQ) STAGE(cur ^ 1, k0 + 32);

    bf16x8 pf[4], af[4];
#pragma unroll
    for (int m = 0; m < 4; ++m) pf[m] = *(const bf16x8*)&ldsP[cur][(rowP + m * 16) * 32 + kch];
#pragma unroll
    for (int n = 0; n < 4; ++n) af[n] = *(const bf16x8*)&ldsA[cur][(rowA + n * 16) * 32 + kch];
#pragma unroll
    for (int m = 0; m < 4; ++m) {
#pragma unroll
      for (int n = 0; n < 4; ++n)
        acc[m][n] = __builtin_amdgcn_mfma_f32_16x16x32_bf16(pf[m], af[n], acc[m][n], 0, 0, 0);
      accd[m] = __builtin_amdgcn_mfma_f32_16x16x32_bf16(pf[m], onesf, accd[m], 0, 0, 0);
    }

    __syncthreads();
    cur ^= 1;
  }
#undef STAGE

  float* ob = out + (size_t)b * SEQ * DIM;
#pragma unroll
  for (int m = 0; m < 4; ++m) {
#pragma unroll
    for (int j = 0; j < 4; ++j) {
      const int ql = wr * 64 + m * 16 + (lane >> 4) * 4 + j;
      const float sc2 = 1.0f / (accd[m][j] + EPS_K);
#pragma unroll
      for (int n = 0; n < 4; ++n) {
        const int dl = d0 + wc * 64 + n * 16 + (lane & 15);
        ob[(size_t)(q0 + ql) * DIM + dl] = acc[m][n][j] * sc2;
      }
    }
  }
}

// ---------------------------------------------------------------------------
extern "C" void kernel_launch(void* const* d_in, const int* in_sizes, int n_in,
                              void* d_out, int out_size, void* d_ws, size_t ws_size,
                              hipStream_t stream) {
  (void)in_sizes; (void)n_in; (void)out_size; (void)ws_size;
  const float* A    = (const float*)d_in[0];
  const int*   mask = (const int*)d_in[1];
  float*       out  = (float*)d_out;

  char* ws = (char*)d_ws;
  const size_t NB_AB = (size_t)BATCH * SEQ * DIM * 2;   // 12,582,912
  const size_t NB_AT = NB_AB;
  uint16_t* ab = (uint16_t*)(ws);
  uint16_t* at = (uint16_t*)(ws + NB_AB);
  uint16_t* P  = (uint16_t*)(ws + NB_AB + NB_AT);

  dim3 blk(256);
  convert_kernel<<<dim3(DIM / 64, SEQ / 64, BATCH), blk, 0, stream>>>(A, ab, at);
  scores_kernel<<<dim3(64 * BATCH), blk, 0, stream>>>(ab, mask, P);
  out_kernel<<<dim3(48 * BATCH), blk, 0, stream>>>(P, at, out);
}